// Round 14
// baseline (324.137 us; speedup 1.0000x reference)
//
#include <hip/hip_runtime.h>
#include <hip/hip_bf16.h>
#include <math.h>
#include <stdint.h>

typedef unsigned short u16;
typedef __attribute__((ext_vector_type(8))) short bfrag;      // 8 bf16 = 4 VGPR
typedef __attribute__((ext_vector_type(4))) float f32x4;
typedef __attribute__((ext_vector_type(8))) unsigned short u16x8;
typedef __attribute__((ext_vector_type(4))) unsigned short u16x4;

#define BB 16
#define CC 128
#define HH 128
#define WW 128
#define EPSV 1e-5f
#define NEG 0.1f
#define PW 130           // padded width/height (1-px zero border)

__device__ __forceinline__ float bf2f(u16 u) {
    unsigned int x = ((unsigned int)u) << 16;
    return __builtin_bit_cast(float, x);
}
__device__ __forceinline__ u16 f2bf(float f) {   // RNE
    unsigned int x = __builtin_bit_cast(unsigned int, f);
    unsigned int r = x + 0x7fffu + ((x >> 16) & 1u);
    return (u16)(r >> 16);
}
__device__ __forceinline__ void gload_lds16(const void* g, void* l) {
    __builtin_amdgcn_global_load_lds(
        (const __attribute__((address_space(1))) void*)g,
        (__attribute__((address_space(3))) void*)l, 16, 0, 0);
}

// ---------------- zero the 1-px borders of hact and hbuf -------------------
__global__ __launch_bounds__(256)
void border_kernel(u16* __restrict__ a, u16* __restrict__ h) {
    int idx = blockIdx.x * 256 + threadIdx.x;   // 16*516*16 = 132096
    if (idx >= BB * 516 * 16) return;
    int cg = idx & 15;
    int t = idx >> 4;
    int b = t / 516, e = t - b * 516;
    int y, x;
    if (e < 130)      { y = 0;           x = e; }
    else if (e < 260) { y = 129;         x = e - 130; }
    else if (e < 388) { y = e - 260 + 1; x = 0; }
    else              { y = e - 388 + 1; x = 129; }
    size_t o = (((size_t)b * PW + y) * PW + x) * 128 + cg * 8;
    u16x8 z = (u16x8)(u16)0;
    *(u16x8*)&a[o] = z;
    *(u16x8*)&h[o] = z;
}

// ---------------- GroupNorm statistics: one block per (b,g) ----------------
__global__ __launch_bounds__(256)
void gn_stats_kernel(const float* __restrict__ x, float* __restrict__ stats) {
    const int bg = blockIdx.x;                 // 0..511
    const float* base = x + (size_t)bg * 65536;
    float s1 = 0.f, s2 = 0.f;
    for (int i = threadIdx.x; i < 16384; i += 256) {
        float4 v = *(const float4*)&base[i * 4];
        s1 += v.x + v.y + v.z + v.w;
        s2 += v.x * v.x + v.y * v.y + v.z * v.z + v.w * v.w;
    }
    #pragma unroll
    for (int off = 32; off > 0; off >>= 1) {
        s1 += __shfl_down(s1, off);
        s2 += __shfl_down(s2, off);
    }
    __shared__ float rs[8];
    const int wid = threadIdx.x >> 6, lane = threadIdx.x & 63;
    if (lane == 0) { rs[wid * 2] = s1; rs[wid * 2 + 1] = s2; }
    __syncthreads();
    if (threadIdx.x == 0) {
        s1 = rs[0] + rs[2] + rs[4] + rs[6];
        s2 = rs[1] + rs[3] + rs[5] + rs[7];
        float mean = s1 * (1.f / 65536.f);
        float var  = s2 * (1.f / 65536.f) - mean * mean;
        stats[2 * bg]     = mean;
        stats[2 * bg + 1] = rsqrtf(var + EPSV);
    }
}

// --- weight fp32 [co][ci][9] -> bf16 [tap(9)][chunk(4)][g(4)][co(128)][8] ---
__global__ __launch_bounds__(256)
void wconv_kernel(const float* __restrict__ w1, const float* __restrict__ w2,
                  u16* __restrict__ w1t, u16* __restrict__ w2t) {
    int idx = blockIdx.x * 256 + threadIdx.x;      // 147456
    if (idx < 147456) {
        int e  = idx & 7;
        int co = (idx >> 3) & 127;
        int g  = (idx >> 10) & 3;
        int ck = (idx >> 12) & 3;
        int t  = idx >> 14;
        int src = (co * 128 + (ck * 32 + g * 8 + e)) * 9 + t;
        w1t[idx] = f2bf(w1[src]);
        w2t[idx] = f2bf(w2[src]);
    }
}

// ------- small FCs: biastot = te@nfw^T + nf_b + conv1_b ; tmp1 = leaky(kv@kW1^T)
__global__ __launch_bounds__(256)
void small1_kernel(const float* __restrict__ te, const float* __restrict__ nfw,
                   const float* __restrict__ nfbias, const float* __restrict__ c1b,
                   const float* __restrict__ kv, const float* __restrict__ kw1,
                   float* __restrict__ biastot, float* __restrict__ tmp1) {
    const int idx = blockIdx.x * 256 + threadIdx.x;
    if (idx < 1024) {                       // tmp1: (16,64)
        const int b = idx >> 6, j = idx & 63;
        float s = 0.f;
        for (int e = 0; e < 64; ++e) s += kv[b * 64 + e] * kw1[j * 64 + e];
        tmp1[idx] = s >= 0.f ? s : NEG * s;
    } else if (idx < 1024 + 2048) {         // biastot: (16,128)
        const int t = idx - 1024;
        const int b = t >> 7, c = t & 127;
        float s = nfbias[c] + c1b[c];
        for (int e = 0; e < 128; ++e) s += te[b * 128 + e] * nfw[c * 128 + e];
        biastot[t] = s;
    }
}

// kern transposed: kern_t[(b*9 + t)*128 + c] = tmp1[b] . kW2[(c*9+t)]
__global__ __launch_bounds__(256)
void small2_kernel(const float* __restrict__ tmp1, const float* __restrict__ kw2,
                   float* __restrict__ kern_t) {
    const int idx = blockIdx.x * 256 + threadIdx.x;    // 18432
    if (idx < BB * CC * 9) {
        const int b = idx / 1152, rc = idx % 1152;
        const int c = rc / 9, t = rc - c * 9;
        float s = 0.f;
        for (int e = 0; e < 64; ++e) s += tmp1[b * 64 + e] * kw2[rc * 64 + e];
        kern_t[((size_t)b * 9 + t) * 128 + c] = s;
    }
}

// -- GroupNorm apply + Swish, NCHW fp32 -> padded NHWC bf16 (LDS transpose) --
__global__ __launch_bounds__(256)
void gn_apply_kernel(const float* __restrict__ x, const float* __restrict__ gamma,
                     const float* __restrict__ beta, const float* __restrict__ stats,
                     u16* __restrict__ hact) {
    __shared__ u16 s_t[128 * 128];
    const int tid = threadIdx.x;
    const int y = blockIdx.x & 127, b = blockIdx.x >> 7;
    #pragma unroll
    for (int i = 0; i < 16; ++i) {
        int unit = (i << 8) + tid;              // (c, x-quad)
        int c = unit >> 5, xq = unit & 31, xx = xq * 4;
        float4 v = *(const float4*)&x[(((size_t)b * 128 + c) * 128 + y) * 128 + xx];
        int gi = b * 32 + (c >> 2);
        float mean = stats[2 * gi], rstd = stats[2 * gi + 1];
        float ga = gamma[c] * rstd, be = beta[c] - mean * ga;
        float a0 = v.x * ga + be, a1 = v.y * ga + be, a2 = v.z * ga + be, a3 = v.w * ga + be;
        a0 = a0 / (1.f + __expf(-a0)); a1 = a1 / (1.f + __expf(-a1));
        a2 = a2 / (1.f + __expf(-a2)); a3 = a3 / (1.f + __expf(-a3));
        int cs = c ^ ((xq & 15) << 3);          // bank swizzle, keeps 8-groups intact
        s_t[(xx + 0) * 128 + cs] = f2bf(a0);
        s_t[(xx + 1) * 128 + cs] = f2bf(a1);
        s_t[(xx + 2) * 128 + cs] = f2bf(a2);
        s_t[(xx + 3) * 128 + cs] = f2bf(a3);
    }
    __syncthreads();
    #pragma unroll
    for (int i = 0; i < 8; ++i) {
        int unit = (i << 8) + tid;              // (x, c-group)
        int xx = unit >> 4, c0 = (unit & 15) * 8;
        int c0s = c0 ^ (((xx >> 2) & 15) << 3);
        u16x8 v = *(const u16x8*)&s_t[xx * 128 + c0s];
        *(u16x8*)&hact[(((size_t)b * PW + y + 1) * PW + (xx + 1)) * 128 + c0] = v;
    }
}

// ---------------- MFMA implicit-GEMM 3x3 conv, 128->128, SAME --------------
// m201-shape phase schedule: 12 phases = (4 ci-chunks x 3 dy-rows); per phase:
//   vmcnt(KW) -> s_barrier -> [cluster 12 B ds_read_b128] -> [issue stages]
//   -> setprio(1) -> 3x{4 A ds_reads + 16 MFMA} -> setprio(0) -> dw taps.
// Weights in LDS, triple-buffered dyr-rows staged 2 phases ahead; act double-
// buffered staged 3 phases ahead; counted vmcnt never 0 until the last phase.
// FINAL=0: outh(padded NHWC bf16) = conv(act) + biastot[b][co]
// FINAL=1: fused dynamic depthwise from the same s_in tile; epilogue single
//          coalesced write: outf = conv + bias + leaky(dw) + xres.
template <int FINAL>
__global__ __launch_bounds__(512, 2)
void conv_mfma_kernel(const u16* __restrict__ act, const u16* __restrict__ wt,
                      const float* __restrict__ bias, const float* __restrict__ kern_t,
                      const float* __restrict__ xres,
                      float* __restrict__ outf, u16* __restrict__ outh) {
    __shared__ __align__(16) u16 s_in[2][1536 * 8];   // 48 KB
    __shared__ __align__(16) u16 s_w[3][1536 * 8];    // 72 KB
    __shared__ float s_k[1152];                       // 4.6 KB

    const int tid = threadIdx.x;
    const int lane = tid & 63, wid = tid >> 6;
    const int wm = wid & 1, wq = wid >> 1;            // co-half, px-quarter
    const int l15 = lane & 15, l4 = lane >> 4;

    // XCD-chunked swizzle: 1024 blocks -> 128 contiguous per XCD (2 images)
    const int bid0 = blockIdx.x;
    const int bid = ((bid0 & 7) << 7) | (bid0 >> 3);
    const int tx = bid & 7, ty = (bid >> 3) & 7, b = bid >> 6;
    const int x0 = tx * 16, y0 = ty * 16;

    f32x4 acc[4][4];
    #pragma unroll
    for (int mi = 0; mi < 4; ++mi)
        #pragma unroll
        for (int nj = 0; nj < 4; ++nj) acc[mi][nj] = (f32x4)(0.f);

    float dw[2][2][4][4];
    if constexpr (FINAL) {
        #pragma unroll
        for (int a0 = 0; a0 < 2; ++a0)
            #pragma unroll
            for (int a1 = 0; a1 < 2; ++a1)
                #pragma unroll
                for (int a2 = 0; a2 < 4; ++a2)
                    #pragma unroll
                    for (int a3 = 0; a3 < 4; ++a3) dw[a0][a1][a2][a3] = 0.f;
        for (int i = tid; i < 1152; i += 512) s_k[i] = kern_t[(size_t)b * 1152 + i];
        __syncthreads();     // drains counters; ledger starts clean
    }

    // ---- hoisted per-thread staging geometry ----
    int in_vofs[3];
    #pragma unroll
    for (int r = 0; r < 3; ++r) {
        int slot = r * 512 + tid;
        int cik = slot / 384;
        int pos = slot - cik * 384;
        if (pos > 323) pos = 323;                 // clamp pad sources
        int row = pos / 18, col = pos - row * 18;
        in_vofs[r] = (row * PW + col) * 128 + cik * 8;       // u16 units
    }
    const u16* in_base = act + (((size_t)b * PW + y0) * PW + x0) * 128;
    int w_vofs[3];
    #pragma unroll
    for (int r = 0; r < 3; ++r) {
        int slot = r * 512 + tid;
        int tapL = slot >> 9;
        int g    = (slot >> 7) & 3;
        int co   = slot & 127;
        w_vofs[r] = tapL * 16384 + g * 1024 + co * 8;        // u16 units
    }
    const int ldst = (wid << 6) * 8;                          // per-wave LDS base

    auto stage_in = [&](int buf, int ci0) {
        #pragma unroll
        for (int r = 0; r < 3; ++r)
            gload_lds16(in_base + ci0 + in_vofs[r], &s_in[buf][r * 512 * 8 + ldst]);
    };
    // phofs = dyr*49152 + ck*4096 (compile-time literal at each call site)
    auto stage_w = [&](int bufi, int phofs) {
        #pragma unroll
        for (int r = 0; r < 3; ++r)
            gload_lds16(wt + phofs + w_vofs[r], &s_w[bufi][r * 512 * 8 + ldst]);
    };

    const int awbase = (l4 * 128 + wm * 64 + l15) * 8;              // u16 units
    const int bbase  = (l4 * 384 + (wq * 4) * 18 + l15) * 8;

    auto dwcomp = [&](int ck, int dyr) {
        if constexpr (FINAL) {
            if ((ck >> 1) == wm) {
                const int mih = ck & 1;
                const u16* sb = &s_in[ck & 1][0];
                #pragma unroll
                for (int mm = 0; mm < 2; ++mm) {
                    const int cik = 2 * mm + (l4 >> 1);
                    const int e0 = (l4 & 1) * 4;
                    const int cb = ck * 32 + mm * 16 + l4 * 4;
                    #pragma unroll
                    for (int dx = 0; dx < 3; ++dx) {
                        const int tap = dyr * 3 + dx;
                        float4 kk = *(const float4*)&s_k[tap * 128 + cb];
                        #pragma unroll
                        for (int nj = 0; nj < 4; ++nj) {
                            const int row = wq * 4 + nj + dyr;
                            const int col = l15 + dx;
                            u16x4 hv = *(const u16x4*)
                                &sb[(cik * 384 + row * 18 + col) * 8 + e0];
                            dw[mih][mm][nj][0] += bf2f(hv[0]) * kk.x;
                            dw[mih][mm][nj][1] += bf2f(hv[1]) * kk.y;
                            dw[mih][mm][nj][2] += bf2f(hv[2]) * kk.z;
                            dw[mih][mm][nj][3] += bf2f(hv[3]) * kk.w;
                        }
                    }
                }
            }
        }
    };

    // prologue: act(chunk0) + w rows for phases 0,1 -> 9 loads/wave in flight
    stage_in(0, 0);
    stage_w(0, 0);           // p0: (ck0, dyr0)
    stage_w(1, 49152);       // p1: (ck0, dyr1)

    // Phase p: wait own counted vmcnt (phase-p inputs retired), barrier,
    // CLUSTER the 12 B-frag ds_reads, issue next stages, then the MFMA block.
#define PHASE(p, c, dyr, KW)                                                   \
    {                                                                          \
        asm volatile("s_waitcnt vmcnt(" #KW ")" ::: "memory");                 \
        __builtin_amdgcn_s_barrier();                                          \
        const u16* sbc = &s_in[(c) & 1][0];                                    \
        const int bo = bbase + (dyr) * 144;                                    \
        bfrag B00 = *(const bfrag*)&sbc[bo];                                   \
        bfrag B01 = *(const bfrag*)&sbc[bo + 144];                             \
        bfrag B02 = *(const bfrag*)&sbc[bo + 288];                             \
        bfrag B03 = *(const bfrag*)&sbc[bo + 432];                             \
        bfrag B10 = *(const bfrag*)&sbc[bo + 8];                               \
        bfrag B11 = *(const bfrag*)&sbc[bo + 152];                             \
        bfrag B12 = *(const bfrag*)&sbc[bo + 296];                             \
        bfrag B13 = *(const bfrag*)&sbc[bo + 440];                             \
        bfrag B20 = *(const bfrag*)&sbc[bo + 16];                              \
        bfrag B21 = *(const bfrag*)&sbc[bo + 160];                             \
        bfrag B22 = *(const bfrag*)&sbc[bo + 304];                             \
        bfrag B23 = *(const bfrag*)&sbc[bo + 448];                             \
        if ((p) + 2 < 12)                                                      \
            stage_w(((p) + 2) % 3,                                             \
                    ((((p) + 2) % 3) * 49152 + (((p) + 2) / 3) * 4096));       \
        if ((dyr) == 1 && (c) < 3) stage_in(((c) + 1) & 1, ((c) + 1) * 32);    \
        const u16* swp = &s_w[(p) % 3][0];                                     \
        __builtin_amdgcn_s_setprio(1);                                         \
        {                                                                      \
            bfrag a0 = *(const bfrag*)&swp[awbase];                            \
            bfrag a1 = *(const bfrag*)&swp[awbase + 128];                      \
            bfrag a2 = *(const bfrag*)&swp[awbase + 256];                      \
            bfrag a3 = *(const bfrag*)&swp[awbase + 384];                      \
            acc[0][0] = __builtin_amdgcn_mfma_f32_16x16x32_bf16(a0, B00, acc[0][0], 0, 0, 0); \
            acc[0][1] = __builtin_amdgcn_mfma_f32_16x16x32_bf16(a0, B01, acc[0][1], 0, 0, 0); \
            acc[0][2] = __builtin_amdgcn_mfma_f32_16x16x32_bf16(a0, B02, acc[0][2], 0, 0, 0); \
            acc[0][3] = __builtin_amdgcn_mfma_f32_16x16x32_bf16(a0, B03, acc[0][3], 0, 0, 0); \
            acc[1][0] = __builtin_amdgcn_mfma_f32_16x16x32_bf16(a1, B00, acc[1][0], 0, 0, 0); \
            acc[1][1] = __builtin_amdgcn_mfma_f32_16x16x32_bf16(a1, B01, acc[1][1], 0, 0, 0); \
            acc[1][2] = __builtin_amdgcn_mfma_f32_16x16x32_bf16(a1, B02, acc[1][2], 0, 0, 0); \
            acc[1][3] = __builtin_amdgcn_mfma_f32_16x16x32_bf16(a1, B03, acc[1][3], 0, 0, 0); \
            acc[2][0] = __builtin_amdgcn_mfma_f32_16x16x32_bf16(a2, B00, acc[2][0], 0, 0, 0); \
            acc[2][1] = __builtin_amdgcn_mfma_f32_16x16x32_bf16(a2, B01, acc[2][1], 0, 0, 0); \
            acc[2][2] = __builtin_amdgcn_mfma_f32_16x16x32_bf16(a2, B02, acc[2][2], 0, 0, 0); \
            acc[2][3] = __builtin_amdgcn_mfma_f32_16x16x32_bf16(a2, B03, acc[2][3], 0, 0, 0); \
            acc[3][0] = __builtin_amdgcn_mfma_f32_16x16x32_bf16(a3, B00, acc[3][0], 0, 0, 0); \
            acc[3][1] = __builtin_amdgcn_mfma_f32_16x16x32_bf16(a3, B01, acc[3][1], 0, 0, 0); \
            acc[3][2] = __builtin_amdgcn_mfma_f32_16x16x32_bf16(a3, B02, acc[3][2], 0, 0, 0); \
            acc[3][3] = __builtin_amdgcn_mfma_f32_16x16x32_bf16(a3, B03, acc[3][3], 0, 0, 0); \
        }                                                                      \
        {                                                                      \
            bfrag a0 = *(const bfrag*)&swp[awbase + 4096];                     \
            bfrag a1 = *(const bfrag*)&swp[awbase + 4224];                     \
            bfrag a2 = *(const bfrag*)&swp[awbase + 4352];                     \
            bfrag a3 = *(const bfrag*)&swp[awbase + 4480];                     \
            acc[0][0] = __builtin_amdgcn_mfma_f32_16x16x32_bf16(a0, B10, acc[0][0], 0, 0, 0); \
            acc[0][1] = __builtin_amdgcn_mfma_f32_16x16x32_bf16(a0, B11, acc[0][1], 0, 0, 0); \
            acc[0][2] = __builtin_amdgcn_mfma_f32_16x16x32_bf16(a0, B12, acc[0][2], 0, 0, 0); \
            acc[0][3] = __builtin_amdgcn_mfma_f32_16x16x32_bf16(a0, B13, acc[0][3], 0, 0, 0); \
            acc[1][0] = __builtin_amdgcn_mfma_f32_16x16x32_bf16(a1, B10, acc[1][0], 0, 0, 0); \
            acc[1][1] = __builtin_amdgcn_mfma_f32_16x16x32_bf16(a1, B11, acc[1][1], 0, 0, 0); \
            acc[1][2] = __builtin_amdgcn_mfma_f32_16x16x32_bf16(a1, B12, acc[1][2], 0, 0, 0); \
            acc[1][3] = __builtin_amdgcn_mfma_f32_16x16x32_bf16(a1, B13, acc[1][3], 0, 0, 0); \
            acc[2][0] = __builtin_amdgcn_mfma_f32_16x16x32_bf16(a2, B10, acc[2][0], 0, 0, 0); \
            acc[2][1] = __builtin_amdgcn_mfma_f32_16x16x32_bf16(a2, B11, acc[2][1], 0, 0, 0); \
            acc[2][2] = __builtin_amdgcn_mfma_f32_16x16x32_bf16(a2, B12, acc[2][2], 0, 0, 0); \
            acc[2][3] = __builtin_amdgcn_mfma_f32_16x16x32_bf16(a2, B13, acc[2][3], 0, 0, 0); \
            acc[3][0] = __builtin_amdgcn_mfma_f32_16x16x32_bf16(a3, B10, acc[3][0], 0, 0, 0); \
            acc[3][1] = __builtin_amdgcn_mfma_f32_16x16x32_bf16(a3, B11, acc[3][1], 0, 0, 0); \
            acc[3][2] = __builtin_amdgcn_mfma_f32_16x16x32_bf16(a3, B12, acc[3][2], 0, 0, 0); \
            acc[3][3] = __builtin_amdgcn_mfma_f32_16x16x32_bf16(a3, B13, acc[3][3], 0, 0, 0); \
        }                                                                      \
        {                                                                      \
            bfrag a0 = *(const bfrag*)&swp[awbase + 8192];                     \
            bfrag a1 = *(const bfrag*)&swp[awbase + 8320];                     \
            bfrag a2 = *(const bfrag*)&swp[awbase + 8448];                     \
            bfrag a3 = *(const bfrag*)&swp[awbase + 8576];                     \
            acc[0][0] = __builtin_amdgcn_mfma_f32_16x16x32_bf16(a0, B20, acc[0][0], 0, 0, 0); \
            acc[0][1] = __builtin_amdgcn_mfma_f32_16x16x32_bf16(a0, B21, acc[0][1], 0, 0, 0); \
            acc[0][2] = __builtin_amdgcn_mfma_f32_16x16x32_bf16(a0, B22, acc[0][2], 0, 0, 0); \
            acc[0][3] = __builtin_amdgcn_mfma_f32_16x16x32_bf16(a0, B23, acc[0][3], 0, 0, 0); \
            acc[1][0] = __builtin_amdgcn_mfma_f32_16x16x32_bf16(a1, B20, acc[1][0], 0, 0, 0); \
            acc[1][1] = __builtin_amdgcn_mfma_f32_16x16x32_bf16(a1, B21, acc[1][1], 0, 0, 0); \
            acc[1][2] = __builtin_amdgcn_mfma_f32_16x16x32_bf16(a1, B22, acc[1][2], 0, 0, 0); \
            acc[1][3] = __builtin_amdgcn_mfma_f32_16x16x32_bf16(a1, B23, acc[1][3], 0, 0, 0); \
            acc[2][0] = __builtin_amdgcn_mfma_f32_16x16x32_bf16(a2, B20, acc[2][0], 0, 0, 0); \
            acc[2][1] = __builtin_amdgcn_mfma_f32_16x16x32_bf16(a2, B21, acc[2][1], 0, 0, 0); \
            acc[2][2] = __builtin_amdgcn_mfma_f32_16x16x32_bf16(a2, B22, acc[2][2], 0, 0, 0); \
            acc[2][3] = __builtin_amdgcn_mfma_f32_16x16x32_bf16(a2, B23, acc[2][3], 0, 0, 0); \
            acc[3][0] = __builtin_amdgcn_mfma_f32_16x16x32_bf16(a3, B20, acc[3][0], 0, 0, 0); \
            acc[3][1] = __builtin_amdgcn_mfma_f32_16x16x32_bf16(a3, B21, acc[3][1], 0, 0, 0); \
            acc[3][2] = __builtin_amdgcn_mfma_f32_16x16x32_bf16(a3, B22, acc[3][2], 0, 0, 0); \
            acc[3][3] = __builtin_amdgcn_mfma_f32_16x16x32_bf16(a3, B23, acc[3][3], 0, 0, 0); \
        }                                                                      \
        __builtin_amdgcn_s_setprio(0);                                         \
        dwcomp((c), (dyr));                                                    \
    }

    PHASE(0, 0, 0, 3)  PHASE(1, 0, 1, 3)  PHASE(2, 0, 2, 6)
    PHASE(3, 1, 0, 3)  PHASE(4, 1, 1, 3)  PHASE(5, 1, 2, 6)
    PHASE(6, 2, 0, 3)  PHASE(7, 2, 1, 3)  PHASE(8, 2, 2, 6)
    PHASE(9, 3, 0, 3)  PHASE(10, 3, 1, 3) PHASE(11, 3, 2, 0)
#undef PHASE

    // ---- epilogue ----
    if (!FINAL) {
        const float* bb = bias + b * 128;
        #pragma unroll
        for (int mi = 0; mi < 4; ++mi) {
            const int cb = wm * 64 + mi * 16 + l4 * 4;
            float4 bv4 = *(const float4*)&bb[cb];
            #pragma unroll
            for (int nj = 0; nj < 4; ++nj) {
                int y = y0 + wq * 4 + nj, xx = x0 + l15;
                u16x4 pk;
                pk[0] = f2bf(acc[mi][nj][0] + bv4.x);
                pk[1] = f2bf(acc[mi][nj][1] + bv4.y);
                pk[2] = f2bf(acc[mi][nj][2] + bv4.z);
                pk[3] = f2bf(acc[mi][nj][3] + bv4.w);
                *(u16x4*)&outh[(((size_t)b * PW + y + 1) * PW + (xx + 1)) * 128 + cb] = pk;
            }
        }
    } else {
        #pragma unroll
        for (int mi = 0; mi < 4; ++mi) {
            const int cb = wm * 64 + mi * 16 + l4 * 4;
            float4 bv4 = *(const float4*)&bias[cb];
            #pragma unroll
            for (int nj = 0; nj < 4; ++nj) {
                int y = y0 + wq * 4 + nj, xx = x0 + l15;
                size_t obase = (((size_t)b * 128 + cb) * 128 + y) * 128 + xx;
                #pragma unroll
                for (int j = 0; j < 4; ++j) {
                    float d = dw[mi >> 1][mi & 1][nj][j];
                    d = d >= 0.f ? d : NEG * d;
                    float bj = (j == 0) ? bv4.x : (j == 1) ? bv4.y : (j == 2) ? bv4.z : bv4.w;
                    outf[obase + (size_t)j * 16384] =
                        acc[mi][nj][j] + bj + d + xres[obase + (size_t)j * 16384];
                }
            }
        }
    }
}

extern "C" void kernel_launch(void* const* d_in, const int* in_sizes, int n_in,
                              void* d_out, int out_size, void* d_ws, size_t ws_size,
                              hipStream_t stream) {
    const float* x        = (const float*)d_in[0];
    const float* te       = (const float*)d_in[1];
    const float* kv       = (const float*)d_in[2];
    const float* gn1_g    = (const float*)d_in[3];
    const float* gn1_b    = (const float*)d_in[4];
    const float* conv1_w  = (const float*)d_in[5];
    const float* conv1_b  = (const float*)d_in[6];
    const float* nf_w     = (const float*)d_in[7];
    const float* nf_b     = (const float*)d_in[8];
    const float* kW1      = (const float*)d_in[9];
    const float* kW2      = (const float*)d_in[10];
    const float* daconv_w = (const float*)d_in[11];
    const float* daconv_b = (const float*)d_in[12];

    float* out = (float*)d_out;

    // workspace: kern_t, w2t, hbuf (padded)
    float* kern  = (float*)d_ws;                         // 18432 f32 ([b][tap][c])
    u16*   w2t   = (u16*)(kern + 18432);                 // 147456 u16
    u16*   hbuf  = (u16*)(kern + 92160);                 // 16*130*130*128 u16 (69.2 MB)

    // temps dead before conv2's overwrite of d_out
    u16*   hact    = (u16*)out;                          // padded NHWC
    float* up      = out + 17500160;
    float* stats   = up;                                 // 1024
    float* biastot = up + 1024;                          // 2048
    float* tmp1    = up + 3072;                          // 1024
    u16*   w1t     = (u16*)(up + 4096);                  // 147456 u16

    border_kernel<<<dim3(516), dim3(256), 0, stream>>>(hact, hbuf);
    gn_stats_kernel<<<dim3(512), dim3(256), 0, stream>>>(x, stats);
    wconv_kernel<<<dim3(576), dim3(256), 0, stream>>>(conv1_w, daconv_w, w1t, w2t);
    small1_kernel<<<dim3(12), dim3(256), 0, stream>>>(te, nf_w, nf_b, conv1_b, kv, kW1,
                                                      biastot, tmp1);
    small2_kernel<<<dim3(72), dim3(256), 0, stream>>>(tmp1, kW2, kern);
    gn_apply_kernel<<<dim3(2048), dim3(256), 0, stream>>>(x, gn1_g, gn1_b, stats, hact);

    // conv1: hbuf = conv(hact) + biastot   (padded NHWC bf16)
    conv_mfma_kernel<0><<<dim3(1024), dim3(512), 0, stream>>>(
        hact, w1t, biastot, nullptr, nullptr, nullptr, hbuf);
    // conv2 (+fused dynamic depthwise + residual):
    //   out = conv(hbuf) + daconv_b + leaky(dw(hbuf,kern)) + x
    conv_mfma_kernel<1><<<dim3(1024), dim3(512), 0, stream>>>(
        hbuf, w2t, daconv_b, kern, x, out, nullptr);
}

// Round 15
// 290.003 us; speedup vs baseline: 1.1177x; 1.1177x over previous
//
#include <hip/hip_runtime.h>
#include <hip/hip_bf16.h>
#include <math.h>
#include <stdint.h>

typedef unsigned short u16;
typedef __attribute__((ext_vector_type(8))) short bfrag;      // 8 bf16 = 4 VGPR
typedef __attribute__((ext_vector_type(4))) float f32x4;
typedef __attribute__((ext_vector_type(8))) unsigned short u16x8;
typedef __attribute__((ext_vector_type(4))) unsigned short u16x4;

#define BB 16
#define CC 128
#define HH 128
#define WW 128
#define EPSV 1e-5f
#define NEG 0.1f
#define PW 130           // padded width/height (1-px zero border)

__device__ __forceinline__ float bf2f(u16 u) {
    unsigned int x = ((unsigned int)u) << 16;
    return __builtin_bit_cast(float, x);
}
__device__ __forceinline__ u16 f2bf(float f) {   // RNE
    unsigned int x = __builtin_bit_cast(unsigned int, f);
    unsigned int r = x + 0x7fffu + ((x >> 16) & 1u);
    return (u16)(r >> 16);
}
__device__ __forceinline__ void gload_lds16(const void* g, void* l) {
    __builtin_amdgcn_global_load_lds(
        (const __attribute__((address_space(1))) void*)g,
        (__attribute__((address_space(3))) void*)l, 16, 0, 0);
}

// ---------------- merged prep kernel -----------------------------------
// blocks [0,512):    gn_stats (one block per (b,g))
// blocks [512,1088): wconv  (fp32 [co][ci][9] -> bf16 [tap][ck][g][co][8])
// blocks [1088,1604): border zero of hact+hbuf
// blocks [1604,1612): biastot = te@nfw^T + nf_b + conv1_b
// blocks [1612,1628): kern_t (recomputes tmp1 in-block; one block per b)
__global__ __launch_bounds__(256)
void prep_kernel(const float* __restrict__ x, float* __restrict__ stats,
                 const float* __restrict__ w1, const float* __restrict__ w2,
                 u16* __restrict__ w1t, u16* __restrict__ w2t,
                 u16* __restrict__ hact, u16* __restrict__ hbuf,
                 const float* __restrict__ te, const float* __restrict__ nfw,
                 const float* __restrict__ nfbias, const float* __restrict__ c1b,
                 float* __restrict__ biastot,
                 const float* __restrict__ kv, const float* __restrict__ kw1,
                 const float* __restrict__ kw2, float* __restrict__ kern_t) {
    __shared__ float rs[8];
    __shared__ float s_t1[64];
    const int blk = blockIdx.x;
    const int tid = threadIdx.x;

    if (blk < 512) {                                    // ---- gn_stats ----
        const int bg = blk;
        const float* base = x + (size_t)bg * 65536;
        float s1 = 0.f, s2 = 0.f;
        for (int i = tid; i < 16384; i += 256) {
            float4 v = *(const float4*)&base[i * 4];
            s1 += v.x + v.y + v.z + v.w;
            s2 += v.x * v.x + v.y * v.y + v.z * v.z + v.w * v.w;
        }
        #pragma unroll
        for (int off = 32; off > 0; off >>= 1) {
            s1 += __shfl_down(s1, off);
            s2 += __shfl_down(s2, off);
        }
        const int wid = tid >> 6, lane = tid & 63;
        if (lane == 0) { rs[wid * 2] = s1; rs[wid * 2 + 1] = s2; }
        __syncthreads();
        if (tid == 0) {
            s1 = rs[0] + rs[2] + rs[4] + rs[6];
            s2 = rs[1] + rs[3] + rs[5] + rs[7];
            float mean = s1 * (1.f / 65536.f);
            float var  = s2 * (1.f / 65536.f) - mean * mean;
            stats[2 * bg]     = mean;
            stats[2 * bg + 1] = rsqrtf(var + EPSV);
        }
    } else if (blk < 1088) {                            // ---- wconv ----
        int idx = (blk - 512) * 256 + tid;              // < 147456
        int e  = idx & 7;
        int co = (idx >> 3) & 127;
        int g  = (idx >> 10) & 3;
        int ck = (idx >> 12) & 3;
        int t  = idx >> 14;
        int src = (co * 128 + (ck * 32 + g * 8 + e)) * 9 + t;
        w1t[idx] = f2bf(w1[src]);
        w2t[idx] = f2bf(w2[src]);
    } else if (blk < 1604) {                            // ---- border ----
        int idx = (blk - 1088) * 256 + tid;             // < 132096
        int cg = idx & 15;
        int t = idx >> 4;
        int b = t / 516, e = t - b * 516;
        int y, xx;
        if (e < 130)      { y = 0;           xx = e; }
        else if (e < 260) { y = 129;         xx = e - 130; }
        else if (e < 388) { y = e - 260 + 1; xx = 0; }
        else              { y = e - 388 + 1; xx = 129; }
        size_t o = (((size_t)b * PW + y) * PW + xx) * 128 + cg * 8;
        u16x8 z = (u16x8)(u16)0;
        *(u16x8*)&hact[o] = z;
        *(u16x8*)&hbuf[o] = z;
    } else if (blk < 1612) {                            // ---- biastot ----
        int idx = (blk - 1604) * 256 + tid;             // < 2048
        const int b = idx >> 7, c = idx & 127;
        float s = nfbias[c] + c1b[c];
        for (int e = 0; e < 128; ++e) s += te[b * 128 + e] * nfw[c * 128 + e];
        biastot[idx] = s;
    } else {                                            // ---- kern_t ----
        const int b = blk - 1612;                       // one block per b
        if (tid < 64) {
            float s = 0.f;
            for (int e = 0; e < 64; ++e) s += kv[b * 64 + e] * kw1[tid * 64 + e];
            s_t1[tid] = s >= 0.f ? s : NEG * s;
        }
        __syncthreads();
        for (int i = tid; i < 1152; i += 256) {
            float s = 0.f;
            for (int e = 0; e < 64; ++e) s += s_t1[e] * kw2[(size_t)i * 64 + e];
            int c = i / 9, t = i - c * 9;
            kern_t[((size_t)b * 9 + t) * 128 + c] = s;
        }
    }
}

// -- GroupNorm apply + Swish, NCHW fp32 -> padded NHWC bf16 (LDS transpose) --
__global__ __launch_bounds__(256)
void gn_apply_kernel(const float* __restrict__ x, const float* __restrict__ gamma,
                     const float* __restrict__ beta, const float* __restrict__ stats,
                     u16* __restrict__ hact) {
    __shared__ u16 s_t[128 * 128];
    const int tid = threadIdx.x;
    const int y = blockIdx.x & 127, b = blockIdx.x >> 7;
    #pragma unroll
    for (int i = 0; i < 16; ++i) {
        int unit = (i << 8) + tid;              // (c, x-quad)
        int c = unit >> 5, xq = unit & 31, xx = xq * 4;
        float4 v = *(const float4*)&x[(((size_t)b * 128 + c) * 128 + y) * 128 + xx];
        int gi = b * 32 + (c >> 2);
        float mean = stats[2 * gi], rstd = stats[2 * gi + 1];
        float ga = gamma[c] * rstd, be = beta[c] - mean * ga;
        float a0 = v.x * ga + be, a1 = v.y * ga + be, a2 = v.z * ga + be, a3 = v.w * ga + be;
        a0 = a0 / (1.f + __expf(-a0)); a1 = a1 / (1.f + __expf(-a1));
        a2 = a2 / (1.f + __expf(-a2)); a3 = a3 / (1.f + __expf(-a3));
        int cs = c ^ ((xq & 15) << 3);          // bank swizzle, keeps 8-groups intact
        s_t[(xx + 0) * 128 + cs] = f2bf(a0);
        s_t[(xx + 1) * 128 + cs] = f2bf(a1);
        s_t[(xx + 2) * 128 + cs] = f2bf(a2);
        s_t[(xx + 3) * 128 + cs] = f2bf(a3);
    }
    __syncthreads();
    #pragma unroll
    for (int i = 0; i < 8; ++i) {
        int unit = (i << 8) + tid;              // (x, c-group)
        int xx = unit >> 4, c0 = (unit & 15) * 8;
        int c0s = c0 ^ (((xx >> 2) & 15) << 3);
        u16x8 v = *(const u16x8*)&s_t[xx * 128 + c0s];
        *(u16x8*)&hact[(((size_t)b * PW + y + 1) * PW + (xx + 1)) * 128 + c0] = v;
    }
}

// ---------------- conv1: low-register / high-occupancy variant -------------
// 512 threads / 8 waves; block tile 16x x 8y px x 128 co; wave = 32co x 64px;
// acc[2][4] = 32 regs -> target <=128 unified regs -> 4 waves/SIMD (2 blk/CU).
// Weights global->VGPR (L2-hot, 2 b128 per tap); LDS = act only (2 x 16 KB).
// One barrier per ci-chunk; stage visibility via in-order vmcnt retirement
// (compiler A-load waits drain the older global_load_lds stages).
__global__ __launch_bounds__(512, 4)
void conv1_mfma_kernel(const u16* __restrict__ act, const u16* __restrict__ wt,
                       const float* __restrict__ bias, u16* __restrict__ outh) {
    __shared__ __align__(16) u16 s_in[2][1024 * 8];   // [buf][slot(720 valid,1024 pad)][8]

    const int tid = threadIdx.x;
    const int lane = tid & 63, wid = tid >> 6;
    const int wm = wid & 3, wq = wid >> 2;            // co-quarter(32), px-half(64)
    const int l15 = lane & 15, l4 = lane >> 4;

    // 2048 blocks: 8 tx x 16 ty x 16 b; XCD-chunked swizzle
    const int bid0 = blockIdx.x;
    const int bid = ((bid0 & 7) << 8) | (bid0 >> 3);
    const int tx = bid & 7, ty = (bid >> 3) & 15, b = bid >> 7;
    const int x0 = tx * 16, y0 = ty * 8;

    f32x4 acc[2][4];
    #pragma unroll
    for (int mi = 0; mi < 2; ++mi)
        #pragma unroll
        for (int nj = 0; nj < 4; ++nj) acc[mi][nj] = (f32x4)(0.f);

    // staging geometry: 720 slots = 4 cik x (10 rows x 18 cols); 2 loads/thread
    int in_vofs[2];
    #pragma unroll
    for (int r = 0; r < 2; ++r) {
        int slot = r * 512 + tid;
        if (slot > 719) slot = 719;                  // clamp src; dst pad region
        int cik = slot / 180;
        int pos = slot - cik * 180;
        int row = pos / 18, col = pos - row * 18;
        in_vofs[r] = (row * PW + col) * 128 + cik * 8;
    }
    const u16* in_base = act + (((size_t)b * PW + y0) * PW + x0) * 128;

    auto stage_in = [&](int buf, int ci0) {
        #pragma unroll
        for (int r = 0; r < 2; ++r)
            gload_lds16(in_base + ci0 + in_vofs[r],
                        &s_in[buf][(size_t)(r * 512 + (wid << 6)) * 8]);
    };

    const u16* wlane = wt + l4 * 1024 + (wm * 32 + l15) * 8;
    const int bbase = (l4 * 180 + (wq * 4) * 18 + l15) * 8;

    stage_in(0, 0);
    asm volatile("s_waitcnt vmcnt(0)" ::: "memory");
    __builtin_amdgcn_s_barrier();
    __builtin_amdgcn_sched_barrier(0);

    #pragma unroll
    for (int c = 0; c < 4; ++c) {
        if (c > 0) {
            __builtin_amdgcn_s_barrier();
            __builtin_amdgcn_sched_barrier(0);
        }
        if (c < 3) stage_in((c + 1) & 1, (c + 1) * 32);
        __builtin_amdgcn_sched_barrier(0);

        const u16* sb = &s_in[c & 1][0];
        #pragma unroll
        for (int dyr = 0; dyr < 3; ++dyr) {
            #pragma unroll
            for (int dx = 0; dx < 3; ++dx) {
                const u16* wp = wlane + (size_t)(((dyr * 3 + dx) * 4 + c) * 4096);
                bfrag a0 = *(const bfrag*)(wp);
                bfrag a1 = *(const bfrag*)(wp + 128);
                const int bo = bbase + (dyr * 18 + dx) * 8;
                bfrag b0 = *(const bfrag*)&sb[bo];
                bfrag b1 = *(const bfrag*)&sb[bo + 144];
                bfrag b2 = *(const bfrag*)&sb[bo + 288];
                bfrag b3 = *(const bfrag*)&sb[bo + 432];

                __builtin_amdgcn_s_setprio(1);
                acc[0][0] = __builtin_amdgcn_mfma_f32_16x16x32_bf16(a0, b0, acc[0][0], 0, 0, 0);
                acc[0][1] = __builtin_amdgcn_mfma_f32_16x16x32_bf16(a0, b1, acc[0][1], 0, 0, 0);
                acc[0][2] = __builtin_amdgcn_mfma_f32_16x16x32_bf16(a0, b2, acc[0][2], 0, 0, 0);
                acc[0][3] = __builtin_amdgcn_mfma_f32_16x16x32_bf16(a0, b3, acc[0][3], 0, 0, 0);
                acc[1][0] = __builtin_amdgcn_mfma_f32_16x16x32_bf16(a1, b0, acc[1][0], 0, 0, 0);
                acc[1][1] = __builtin_amdgcn_mfma_f32_16x16x32_bf16(a1, b1, acc[1][1], 0, 0, 0);
                acc[1][2] = __builtin_amdgcn_mfma_f32_16x16x32_bf16(a1, b2, acc[1][2], 0, 0, 0);
                acc[1][3] = __builtin_amdgcn_mfma_f32_16x16x32_bf16(a1, b3, acc[1][3], 0, 0, 0);
                __builtin_amdgcn_s_setprio(0);
            }
        }
    }

    // epilogue: outh = conv + biastot  (padded NHWC bf16)
    const float* bb = bias + b * 128;
    #pragma unroll
    for (int mi = 0; mi < 2; ++mi) {
        const int cb = wm * 32 + mi * 16 + l4 * 4;
        float4 bv4 = *(const float4*)&bb[cb];
        #pragma unroll
        for (int nj = 0; nj < 4; ++nj) {
            int y = y0 + wq * 4 + nj, xx = x0 + l15;
            u16x4 pk;
            pk[0] = f2bf(acc[mi][nj][0] + bv4.x);
            pk[1] = f2bf(acc[mi][nj][1] + bv4.y);
            pk[2] = f2bf(acc[mi][nj][2] + bv4.z);
            pk[3] = f2bf(acc[mi][nj][3] + bv4.w);
            *(u16x4*)&outh[(((size_t)b * PW + y + 1) * PW + (xx + 1)) * 128 + cb] = pk;
        }
    }
}

// ------- conv2 (FINAL): 512-thread, fused dynamic depthwise + residual -----
// (round-13 verified structure, unchanged)
__global__ __launch_bounds__(512, 2)
void conv2_mfma_kernel(const u16* __restrict__ act, const u16* __restrict__ wt,
                       const float* __restrict__ bias, const float* __restrict__ kern_t,
                       const float* __restrict__ xres, float* __restrict__ outf) {
    __shared__ __align__(16) u16 s_in[2][1536 * 8];   // 48 KB
    __shared__ float s_k[1152];                       // 4.6 KB

    const int tid = threadIdx.x;
    const int lane = tid & 63, wid = tid >> 6;
    const int wm = wid & 1, wq = wid >> 1;
    const int l15 = lane & 15, l4 = lane >> 4;

    const int bid0 = blockIdx.x;
    const int bid = ((bid0 & 7) << 7) | (bid0 >> 3);
    const int tx = bid & 7;
    const int x0 = tx * 16;
    const int b_  = bid >> 6;
    const int ty_ = (bid >> 3) & 7;
    const int y0_ = ty_ * 16;

    f32x4 acc[4][4];
    #pragma unroll
    for (int mi = 0; mi < 4; ++mi)
        #pragma unroll
        for (int nj = 0; nj < 4; ++nj) acc[mi][nj] = (f32x4)(0.f);

    float dw[2][2][4][4];
    #pragma unroll
    for (int a0 = 0; a0 < 2; ++a0)
        #pragma unroll
        for (int a1 = 0; a1 < 2; ++a1)
            #pragma unroll
            for (int a2 = 0; a2 < 4; ++a2)
                #pragma unroll
                for (int a3 = 0; a3 < 4; ++a3) dw[a0][a1][a2][a3] = 0.f;

    for (int i = tid; i < 1152; i += 512) s_k[i] = kern_t[(size_t)b_ * 1152 + i];
    __syncthreads();

    int in_vofs[3];
    #pragma unroll
    for (int r = 0; r < 3; ++r) {
        int slot = r * 512 + tid;
        int cik = slot / 384;
        int pos = slot - cik * 384;
        if (pos > 323) pos = 323;
        int row = pos / 18, col = pos - row * 18;
        in_vofs[r] = (row * PW + col) * 128 + cik * 8;
    }
    const u16* in_base = act + (((size_t)b_ * PW + y0_) * PW + x0) * 128;
    const int ldst = (wid << 6) * 8;

    auto stage_in = [&](int buf, int ci0) {
        #pragma unroll
        for (int r = 0; r < 3; ++r)
            gload_lds16(in_base + ci0 + in_vofs[r], &s_in[buf][r * 512 * 8 + ldst]);
    };

    const u16* wlane = wt + l4 * 1024 + (wm * 64 + l15) * 8;
    const int bbase = (l4 * 384 + (wq * 4) * 18 + l15) * 8;

    auto dwcomp = [&](int ck, int dyr) {
        if ((ck >> 1) == wm) {
            const int mih = ck & 1;
            const u16* sb = &s_in[ck & 1][0];
            #pragma unroll
            for (int mm = 0; mm < 2; ++mm) {
                const int cik = 2 * mm + (l4 >> 1);
                const int e0 = (l4 & 1) * 4;
                const int cb = ck * 32 + mm * 16 + l4 * 4;
                #pragma unroll
                for (int dx = 0; dx < 3; ++dx) {
                    const int tap = dyr * 3 + dx;
                    float4 kk = *(const float4*)&s_k[tap * 128 + cb];
                    #pragma unroll
                    for (int nj = 0; nj < 4; ++nj) {
                        const int row = wq * 4 + nj + dyr;
                        const int col = l15 + dx;
                        u16x4 hv = *(const u16x4*)
                            &sb[(cik * 384 + row * 18 + col) * 8 + e0];
                        dw[mih][mm][nj][0] += bf2f(hv[0]) * kk.x;
                        dw[mih][mm][nj][1] += bf2f(hv[1]) * kk.y;
                        dw[mih][mm][nj][2] += bf2f(hv[2]) * kk.z;
                        dw[mih][mm][nj][3] += bf2f(hv[3]) * kk.w;
                    }
                }
            }
        }
    };

    stage_in(0, 0);
    asm volatile("s_waitcnt vmcnt(0)" ::: "memory");
    __builtin_amdgcn_s_barrier();
    __builtin_amdgcn_sched_barrier(0);

    #pragma unroll
    for (int c = 0; c < 4; ++c) {
        if (c > 0) {
            __builtin_amdgcn_s_barrier();
        }
        if (c < 3) {
            stage_in((c + 1) & 1, (c + 1) * 32);
            asm volatile("s_waitcnt vmcnt(3)" ::: "memory");
        }
        __builtin_amdgcn_sched_barrier(0);

        const u16* sb = &s_in[c & 1][0];
        #pragma unroll
        for (int dyr = 0; dyr < 3; ++dyr) {
            bfrag wR[3][4];
            #pragma unroll
            for (int dx = 0; dx < 3; ++dx) {
                const u16* wp = wlane + ((dyr * 3 + dx) * 4 + c) * 4096;
                #pragma unroll
                for (int mi = 0; mi < 4; ++mi)
                    wR[dx][mi] = *(const bfrag*)(wp + mi * 128);
            }
            __builtin_amdgcn_s_setprio(1);
            #pragma unroll
            for (int dx = 0; dx < 3; ++dx) {
                const int bo = bbase + (dyr * 18 + dx) * 8;
                bfrag b0 = *(const bfrag*)&sb[bo];
                bfrag b1 = *(const bfrag*)&sb[bo + 144];
                bfrag b2 = *(const bfrag*)&sb[bo + 288];
                bfrag b3 = *(const bfrag*)&sb[bo + 432];

                acc[0][0] = __builtin_amdgcn_mfma_f32_16x16x32_bf16(wR[dx][0], b0, acc[0][0], 0, 0, 0);
                acc[0][1] = __builtin_amdgcn_mfma_f32_16x16x32_bf16(wR[dx][0], b1, acc[0][1], 0, 0, 0);
                acc[0][2] = __builtin_amdgcn_mfma_f32_16x16x32_bf16(wR[dx][0], b2, acc[0][2], 0, 0, 0);
                acc[0][3] = __builtin_amdgcn_mfma_f32_16x16x32_bf16(wR[dx][0], b3, acc[0][3], 0, 0, 0);
                acc[1][0] = __builtin_amdgcn_mfma_f32_16x16x32_bf16(wR[dx][1], b0, acc[1][0], 0, 0, 0);
                acc[1][1] = __builtin_amdgcn_mfma_f32_16x16x32_bf16(wR[dx][1], b1, acc[1][1], 0, 0, 0);
                acc[1][2] = __builtin_amdgcn_mfma_f32_16x16x32_bf16(wR[dx][1], b2, acc[1][2], 0, 0, 0);
                acc[1][3] = __builtin_amdgcn_mfma_f32_16x16x32_bf16(wR[dx][1], b3, acc[1][3], 0, 0, 0);
                acc[2][0] = __builtin_amdgcn_mfma_f32_16x16x32_bf16(wR[dx][2], b0, acc[2][0], 0, 0, 0);
                acc[2][1] = __builtin_amdgcn_mfma_f32_16x16x32_bf16(wR[dx][2], b1, acc[2][1], 0, 0, 0);
                acc[2][2] = __builtin_amdgcn_mfma_f32_16x16x32_bf16(wR[dx][2], b2, acc[2][2], 0, 0, 0);
                acc[2][3] = __builtin_amdgcn_mfma_f32_16x16x32_bf16(wR[dx][2], b3, acc[2][3], 0, 0, 0);
                acc[3][0] = __builtin_amdgcn_mfma_f32_16x16x32_bf16(wR[dx][3], b0, acc[3][0], 0, 0, 0);
                acc[3][1] = __builtin_amdgcn_mfma_f32_16x16x32_bf16(wR[dx][3], b1, acc[3][1], 0, 0, 0);
                acc[3][2] = __builtin_amdgcn_mfma_f32_16x16x32_bf16(wR[dx][3], b2, acc[3][2], 0, 0, 0);
                acc[3][3] = __builtin_amdgcn_mfma_f32_16x16x32_bf16(wR[dx][3], b3, acc[3][3], 0, 0, 0);
            }
            __builtin_amdgcn_s_setprio(0);
            dwcomp(c, dyr);
        }
    }

    #pragma unroll
    for (int mi = 0; mi < 4; ++mi) {
        const int cb = wm * 64 + mi * 16 + l4 * 4;
        float4 bv4 = *(const float4*)&bias[cb];
        #pragma unroll
        for (int nj = 0; nj < 4; ++nj) {
            int y = y0_ + wq * 4 + nj, xx = x0 + l15;
            size_t obase = (((size_t)b_ * 128 + cb) * 128 + y) * 128 + xx;
            #pragma unroll
            for (int j = 0; j < 4; ++j) {
                float d = dw[mi >> 1][mi & 1][nj][j];
                d = d >= 0.f ? d : NEG * d;
                float bj = (j == 0) ? bv4.x : (j == 1) ? bv4.y : (j == 2) ? bv4.z : bv4.w;
                outf[obase + (size_t)j * 16384] =
                    acc[mi][nj][j] + bj + d + xres[obase + (size_t)j * 16384];
            }
        }
    }
}

extern "C" void kernel_launch(void* const* d_in, const int* in_sizes, int n_in,
                              void* d_out, int out_size, void* d_ws, size_t ws_size,
                              hipStream_t stream) {
    const float* x        = (const float*)d_in[0];
    const float* te       = (const float*)d_in[1];
    const float* kv       = (const float*)d_in[2];
    const float* gn1_g    = (const float*)d_in[3];
    const float* gn1_b    = (const float*)d_in[4];
    const float* conv1_w  = (const float*)d_in[5];
    const float* conv1_b  = (const float*)d_in[6];
    const float* nf_w     = (const float*)d_in[7];
    const float* nf_b     = (const float*)d_in[8];
    const float* kW1      = (const float*)d_in[9];
    const float* kW2      = (const float*)d_in[10];
    const float* daconv_w = (const float*)d_in[11];
    const float* daconv_b = (const float*)d_in[12];

    float* out = (float*)d_out;

    // workspace: kern_t, w2t, hbuf (padded)
    float* kern  = (float*)d_ws;                         // 18432 f32 ([b][tap][c])
    u16*   w2t   = (u16*)(kern + 18432);                 // 147456 u16
    u16*   hbuf  = (u16*)(kern + 92160);                 // 16*130*130*128 u16 (69.2 MB)

    // temps dead before conv2's overwrite of d_out
    u16*   hact    = (u16*)out;                          // padded NHWC
    float* up      = out + 17500160;
    float* stats   = up;                                 // 1024
    float* biastot = up + 1024;                          // 2048
    u16*   w1t     = (u16*)(up + 4096);                  // 147456 u16

    // prep: gn_stats + wconv + border + biastot + kern_t  (one kernel)
    prep_kernel<<<dim3(1628), dim3(256), 0, stream>>>(
        x, stats, conv1_w, daconv_w, w1t, w2t, hact, hbuf,
        te, nf_w, nf_b, conv1_b, biastot, kv, kW1, kW2, kern);
    // gn_apply: hact = swish(GN(x))   (padded NHWC bf16)
    gn_apply_kernel<<<dim3(2048), dim3(256), 0, stream>>>(x, gn1_g, gn1_b, stats, hact);
    // conv1: hbuf = conv(hact) + biastot   (low-reg / high-occupancy variant)
    conv1_mfma_kernel<<<dim3(2048), dim3(512), 0, stream>>>(hact, w1t, biastot, hbuf);
    // conv2 (+fused dynamic depthwise + residual):
    //   out = conv(hbuf) + daconv_b + leaky(dw(hbuf,kern)) + x
    conv2_mfma_kernel<<<dim3(1024), dim3(512), 0, stream>>>(
        hbuf, w2t, daconv_b, kern, x, out);
}